// Round 6
// baseline (255.516 us; speedup 1.0000x reference)
//
#include <hip/hip_runtime.h>
#include <cmath>

// BertEmbeddings: B=8, S=2048, H=768. fp32 in/out.
// R5 history: wave-per-token + __sinf + nt-stores + LDS params = kernel ~47us,
//   latency-bound (VGPR 116 -> 4 waves/SIMD, 15 gathers in flight per wave).
// R6: ONE TOKEN PER 192-THREAD BLOCK (3 waves, 1 float4 chunk per thread).
//   - per-thread gather set 15 -> 5 float4s  => ~60 VGPR, launch_bounds(192,7)
//   - token ids/taus are block-uniform => SGPR s_loads, shared lane offset
//   - params/gamma/beta from global (same addrs every block -> L1 resident)
//   - LN: wave shuffle reduce + 6-float LDS cross-wave reduce
//   Tripwire: WRITE_SIZE/total-dur regression means the 73-reg cap spilled.
static constexpr int B_ = 8;
static constexpr int S_ = 2048;
static constexpr int H_ = 768;            // 192 float4 chunks per row
static constexpr int TOKENS = B_ * S_;    // 16384
static constexpr float LN_EPS = 1e-12f;

typedef float nfloat4 __attribute__((ext_vector_type(4)));

__global__ __launch_bounds__(192, 7) void bert_emb_kernel(
    const int* __restrict__ word_ids,
    const int* __restrict__ modal_ids,
    const int* __restrict__ seg_ids,
    const int* __restrict__ npi_ids,
    const int* __restrict__ posi_ids,
    const float* __restrict__ age_tau,
    const float* __restrict__ delay_tau,
    const float* __restrict__ word_table,
    const float* __restrict__ modal_table,
    const float* __restrict__ seg_table,
    const float* __restrict__ npi_table,
    const float* __restrict__ posi_table,
    const float* __restrict__ age_w,      // [767]
    const float* __restrict__ age_b,      // [767]
    const float* __restrict__ age_w0,     // [1]
    const float* __restrict__ age_b0,     // [1]
    const float* __restrict__ delay_w,    // [767]
    const float* __restrict__ delay_b,    // [767]
    const float* __restrict__ delay_w0,   // [1]
    const float* __restrict__ delay_b0,   // [1]
    const float* __restrict__ ln_gamma,   // [768]
    const float* __restrict__ ln_beta,    // [768]
    float* __restrict__ out)
{
    __shared__ float s_red[6];            // {sum,sq} x 3 waves

    const int token = blockIdx.x;         // one token per block
    const int tid   = threadIdx.x;        // 0..191 == float4 chunk index
    const int wave  = tid >> 6;           // 0..2
    const int lane  = tid & 63;

    // Block-uniform per-token scalars -> compiler emits SGPR loads
    const int wid = word_ids[token];
    const int mid = modal_ids[token];
    const int sid = seg_ids[token];
    const int nid = npi_ids[token];
    const int pid = posi_ids[token];
    const float atau = age_tau[token];
    const float dtau = delay_tau[token];

    // 5 gathered row chunks, one float4 per thread, fully coalesced
    const float4 we = reinterpret_cast<const float4*>(word_table  + (size_t)wid * H_)[tid];
    const float4 me = reinterpret_cast<const float4*>(modal_table + (size_t)mid * H_)[tid];
    const float4 se = reinterpret_cast<const float4*>(seg_table   + (size_t)sid * H_)[tid];
    const float4 ne = reinterpret_cast<const float4*>(npi_table   + (size_t)nid * H_)[tid];
    const float4 pe = reinterpret_cast<const float4*>(posi_table  + (size_t)pid * H_)[tid];

    // time2vec params (same addresses in every block -> L1/L2 resident)
    float4 aw, ab, dw, db;
    if (tid < H_ / 4 - 1) {               // chunks 0..190 fully inside [0,767)
        aw = reinterpret_cast<const float4*>(age_w)[tid];
        ab = reinterpret_cast<const float4*>(age_b)[tid];
        dw = reinterpret_cast<const float4*>(delay_w)[tid];
        db = reinterpret_cast<const float4*>(delay_b)[tid];
    } else {                              // chunk 191: h=764..766 valid, 767 is linear branch
        aw = make_float4(age_w[764],   age_w[765],   age_w[766],   0.0f);
        ab = make_float4(age_b[764],   age_b[765],   age_b[766],   0.0f);
        dw = make_float4(delay_w[764], delay_w[765], delay_w[766], 0.0f);
        db = make_float4(delay_b[764], delay_b[765], delay_b[766], 0.0f);
    }

    float av0 = __sinf(atau * aw.x + ab.x);
    float av1 = __sinf(atau * aw.y + ab.y);
    float av2 = __sinf(atau * aw.z + ab.z);
    float av3 = __sinf(atau * aw.w + ab.w);
    float dv0 = __sinf(dtau * dw.x + db.x);
    float dv1 = __sinf(dtau * dw.y + db.y);
    float dv2 = __sinf(dtau * dw.z + db.z);
    float dv3 = __sinf(dtau * dw.w + db.w);
    if (tid == H_ / 4 - 1) {              // h = 767: linear branch of time2vec
        av3 = atau * age_w0[0]   + age_b0[0];
        dv3 = dtau * delay_w0[0] + delay_b0[0];
    }

    const float e0 = we.x + me.x + se.x + ne.x + pe.x + av0 + dv0;
    const float e1 = we.y + me.y + se.y + ne.y + pe.y + av1 + dv1;
    const float e2 = we.z + me.z + se.z + ne.z + pe.z + av2 + dv2;
    const float e3 = we.w + me.w + se.w + ne.w + pe.w + av3 + dv3;

    float ssum = e0 + e1 + e2 + e3;
    float ssq  = e0 * e0 + e1 * e1 + e2 * e2 + e3 * e3;

    // Wave-level shuffle reduction (64 lanes)
#pragma unroll
    for (int off = 32; off > 0; off >>= 1) {
        ssum += __shfl_down(ssum, off);
        ssq  += __shfl_down(ssq,  off);
    }
    if (lane == 0) {
        s_red[wave * 2 + 0] = ssum;
        s_red[wave * 2 + 1] = ssq;
    }
    __syncthreads();
    const float tsum = s_red[0] + s_red[2] + s_red[4];
    const float tsq  = s_red[1] + s_red[3] + s_red[5];

    const float inv_h = 1.0f / (float)H_;
    const float mu = tsum * inv_h;
    const float var = tsq * inv_h - mu * mu;
    const float rstd = rsqrtf(var + LN_EPS);

    const float4 g  = reinterpret_cast<const float4*>(ln_gamma)[tid];
    const float4 bt = reinterpret_cast<const float4*>(ln_beta)[tid];
    nfloat4 o;
    o.x = (e0 - mu) * rstd * g.x + bt.x;
    o.y = (e1 - mu) * rstd * g.y + bt.y;
    o.z = (e2 - mu) * rstd * g.z + bt.z;
    o.w = (e3 - mu) * rstd * g.w + bt.w;
    nfloat4* orow = reinterpret_cast<nfloat4*>(out + (size_t)token * H_);
    __builtin_nontemporal_store(o, &orow[tid]);
}

extern "C" void kernel_launch(void* const* d_in, const int* in_sizes, int n_in,
                              void* d_out, int out_size, void* d_ws, size_t ws_size,
                              hipStream_t stream) {
    const int*   word_ids    = (const int*)  d_in[0];
    const int*   modal_ids   = (const int*)  d_in[1];
    const int*   seg_ids     = (const int*)  d_in[2];
    const int*   npi_ids     = (const int*)  d_in[3];
    const int*   posi_ids    = (const int*)  d_in[4];
    const float* age_tau     = (const float*)d_in[5];
    const float* delay_tau   = (const float*)d_in[6];
    const float* word_table  = (const float*)d_in[7];
    const float* modal_table = (const float*)d_in[8];
    const float* seg_table   = (const float*)d_in[9];
    const float* npi_table   = (const float*)d_in[10];
    const float* posi_table  = (const float*)d_in[11];
    const float* age_w       = (const float*)d_in[12];
    const float* age_b       = (const float*)d_in[13];
    const float* age_w0      = (const float*)d_in[14];
    const float* age_b0      = (const float*)d_in[15];
    const float* delay_w     = (const float*)d_in[16];
    const float* delay_b     = (const float*)d_in[17];
    const float* delay_w0    = (const float*)d_in[18];
    const float* delay_b0    = (const float*)d_in[19];
    const float* ln_gamma    = (const float*)d_in[20];
    const float* ln_beta     = (const float*)d_in[21];
    float* out = (float*)d_out;

    dim3 grid(TOKENS);       // one token per block
    dim3 block(192);         // 3 waves, one float4 chunk per thread
    hipLaunchKernelGGL(bert_emb_kernel, grid, block, 0, stream,
                       word_ids, modal_ids, seg_ids, npi_ids, posi_ids,
                       age_tau, delay_tau,
                       word_table, modal_table, seg_table, npi_table, posi_table,
                       age_w, age_b, age_w0, age_b0,
                       delay_w, delay_b, delay_w0, delay_b0,
                       ln_gamma, ln_beta, out);
}

// Round 7
// 229.855 us; speedup vs baseline: 1.1116x; 1.1116x over previous
//
#include <hip/hip_runtime.h>
#include <cmath>

// BertEmbeddings: B=8, S=2048, H=768. fp32 in/out.
// History:
//  R0 wave-per-token, sinf:            kernel 77us (VALU 25%, VGPR 116)
//  R1 launch_bounds(256,6):            SPILL disaster (WRITE 49->246 MB)
//  R3 __sinf + nt-store + (256,4):     kernel ~58us
//  R4 + LDS params + (256,5):          kernel ~54us  <- best
//  R6 chunk-per-thread (192thr/token): kernel 76us — occupancy 73% but
//     per-wave MLP 5 loads vs 15; occupancy was NOT the constraint. Reverted.
// R7: R4 + readfirstlane-scalarized ids/taus (row bases -> SGPR pairs, one
//     shared lane-offset VGPR, chunk offsets as 13-bit immediates) + all 15
//     gathers flattened/issued before any consume (single vmcnt group).
static constexpr int B_ = 8;
static constexpr int S_ = 2048;
static constexpr int H_ = 768;            // 192 float4 chunks per row
static constexpr int TOKENS = B_ * S_;    // 16384
static constexpr float LN_EPS = 1e-12f;

typedef float nfloat4 __attribute__((ext_vector_type(4)));

__device__ __forceinline__ float rfl_f32(float x) {
    return __uint_as_float(__builtin_amdgcn_readfirstlane(__float_as_uint(x)));
}

__global__ __launch_bounds__(256, 5) void bert_emb_kernel(
    const int* __restrict__ word_ids,
    const int* __restrict__ modal_ids,
    const int* __restrict__ seg_ids,
    const int* __restrict__ npi_ids,
    const int* __restrict__ posi_ids,
    const float* __restrict__ age_tau,
    const float* __restrict__ delay_tau,
    const float* __restrict__ word_table,
    const float* __restrict__ modal_table,
    const float* __restrict__ seg_table,
    const float* __restrict__ npi_table,
    const float* __restrict__ posi_table,
    const float* __restrict__ age_w,      // [767]
    const float* __restrict__ age_b,      // [767]
    const float* __restrict__ age_w0,     // [1]
    const float* __restrict__ age_b0,     // [1]
    const float* __restrict__ delay_w,    // [767]
    const float* __restrict__ delay_b,    // [767]
    const float* __restrict__ delay_w0,   // [1]
    const float* __restrict__ delay_b0,   // [1]
    const float* __restrict__ ln_gamma,   // [768]
    const float* __restrict__ ln_beta,    // [768]
    float* __restrict__ out)
{
    __shared__ __align__(16) float s_aw[H_];
    __shared__ __align__(16) float s_ab[H_];
    __shared__ __align__(16) float s_dw[H_];
    __shared__ __align__(16) float s_db[H_];
    __shared__ __align__(16) float s_g [H_];
    __shared__ __align__(16) float s_bt[H_];

    // Cooperative stage of token-invariant vectors (pad element 767 with 0)
    for (int i = threadIdx.x; i < H_; i += 256) {
        const bool in = (i < H_ - 1);
        s_aw[i] = in ? age_w[i]   : 0.0f;
        s_ab[i] = in ? age_b[i]   : 0.0f;
        s_dw[i] = in ? delay_w[i] : 0.0f;
        s_db[i] = in ? delay_b[i] : 0.0f;
        s_g [i] = ln_gamma[i];
        s_bt[i] = ln_beta[i];
    }
    __syncthreads();

    const int wave = threadIdx.x >> 6;         // 0..3
    const int lane = threadIdx.x & 63;         // 0..63
    const int token = (blockIdx.x << 2) + wave;  // grid = TOKENS/4 exactly

    // Wave-uniform scalars, forced into SGPRs via readfirstlane so the five
    // row base addresses become SGPR pairs (gathers: SGPR base + lane VGPR).
    const int wid = __builtin_amdgcn_readfirstlane(word_ids[token]);
    const int mid = __builtin_amdgcn_readfirstlane(modal_ids[token]);
    const int sid = __builtin_amdgcn_readfirstlane(seg_ids[token]);
    const int nid = __builtin_amdgcn_readfirstlane(npi_ids[token]);
    const int pid = __builtin_amdgcn_readfirstlane(posi_ids[token]);
    const float atau = rfl_f32(age_tau[token]);
    const float dtau = rfl_f32(delay_tau[token]);
    const float aw0 = age_w0[0], ab0 = age_b0[0];
    const float dw0 = delay_w0[0], db0 = delay_b0[0];

    const float4* wrow = reinterpret_cast<const float4*>(word_table  + (size_t)wid * H_);
    const float4* mrow = reinterpret_cast<const float4*>(modal_table + (size_t)mid * H_);
    const float4* srow = reinterpret_cast<const float4*>(seg_table   + (size_t)sid * H_);
    const float4* nrow = reinterpret_cast<const float4*>(npi_table   + (size_t)nid * H_);
    const float4* prow = reinterpret_cast<const float4*>(posi_table  + (size_t)pid * H_);

    // Issue ALL 15 gathers before any consume: one vmcnt group, max MLP.
    const float4 w0 = wrow[lane], w1 = wrow[lane + 64], w2 = wrow[lane + 128];
    const float4 m0 = mrow[lane], m1 = mrow[lane + 64], m2 = mrow[lane + 128];
    const float4 s0 = srow[lane], s1 = srow[lane + 64], s2 = srow[lane + 128];
    const float4 n0 = nrow[lane], n1 = nrow[lane + 64], n2 = nrow[lane + 128];
    const float4 p0 = prow[lane], p1 = prow[lane + 64], p2 = prow[lane + 128];

    const float4* awv = reinterpret_cast<const float4*>(s_aw);
    const float4* abv = reinterpret_cast<const float4*>(s_ab);
    const float4* dwv = reinterpret_cast<const float4*>(s_dw);
    const float4* dbv = reinterpret_cast<const float4*>(s_db);

    float vals[12];
    float ssum = 0.0f, ssq = 0.0f;

    const float4 wcs[3] = {w0, w1, w2};
    const float4 mcs[3] = {m0, m1, m2};
    const float4 scs[3] = {s0, s1, s2};
    const float4 ncs[3] = {n0, n1, n2};
    const float4 pcs[3] = {p0, p1, p2};

#pragma unroll
    for (int c = 0; c < 3; ++c) {
        const int h4 = lane + (c << 6);        // 0..191 (chunk index)
        const float4 we = wcs[c];
        const float4 me = mcs[c];
        const float4 se = scs[c];
        const float4 ne = ncs[c];
        const float4 pe = pcs[c];

        const float4 aw = awv[h4];
        const float4 ab = abv[h4];
        const float4 dw = dwv[h4];
        const float4 db = dbv[h4];

        float av0 = __sinf(atau * aw.x + ab.x);
        float av1 = __sinf(atau * aw.y + ab.y);
        float av2 = __sinf(atau * aw.z + ab.z);
        float av3 = __sinf(atau * aw.w + ab.w);
        float dv0 = __sinf(dtau * dw.x + db.x);
        float dv1 = __sinf(dtau * dw.y + db.y);
        float dv2 = __sinf(dtau * dw.z + db.z);
        float dv3 = __sinf(dtau * dw.w + db.w);
        if (h4 == (H_ / 4 - 1)) {              // h = 767: linear branch of time2vec
            av3 = atau * aw0 + ab0;
            dv3 = dtau * dw0 + db0;
        }

        const float e0 = we.x + me.x + se.x + ne.x + pe.x + av0 + dv0;
        const float e1 = we.y + me.y + se.y + ne.y + pe.y + av1 + dv1;
        const float e2 = we.z + me.z + se.z + ne.z + pe.z + av2 + dv2;
        const float e3 = we.w + me.w + se.w + ne.w + pe.w + av3 + dv3;

        vals[c * 4 + 0] = e0;
        vals[c * 4 + 1] = e1;
        vals[c * 4 + 2] = e2;
        vals[c * 4 + 3] = e3;
        ssum += e0 + e1 + e2 + e3;
        ssq  += e0 * e0 + e1 * e1 + e2 * e2 + e3 * e3;
    }

    // Wave-wide (64-lane) reduction for mean / variance
#pragma unroll
    for (int off = 32; off > 0; off >>= 1) {
        ssum += __shfl_down(ssum, off);
        ssq  += __shfl_down(ssq,  off);
    }
    ssum = __shfl(ssum, 0);
    ssq  = __shfl(ssq,  0);

    const float inv_h = 1.0f / (float)H_;
    const float mu = ssum * inv_h;
    const float var = ssq * inv_h - mu * mu;
    const float rstd = rsqrtf(var + LN_EPS);

    const float4* gv = reinterpret_cast<const float4*>(s_g);
    const float4* bv = reinterpret_cast<const float4*>(s_bt);
    nfloat4* orow = reinterpret_cast<nfloat4*>(out + (size_t)token * H_);

#pragma unroll
    for (int c = 0; c < 3; ++c) {
        const int h4 = lane + (c << 6);
        const float4 g  = gv[h4];
        const float4 bt = bv[h4];
        nfloat4 o;
        o.x = (vals[c * 4 + 0] - mu) * rstd * g.x + bt.x;
        o.y = (vals[c * 4 + 1] - mu) * rstd * g.y + bt.y;
        o.z = (vals[c * 4 + 2] - mu) * rstd * g.z + bt.z;
        o.w = (vals[c * 4 + 3] - mu) * rstd * g.w + bt.w;
        __builtin_nontemporal_store(o, &orow[h4]);
    }
}

extern "C" void kernel_launch(void* const* d_in, const int* in_sizes, int n_in,
                              void* d_out, int out_size, void* d_ws, size_t ws_size,
                              hipStream_t stream) {
    const int*   word_ids    = (const int*)  d_in[0];
    const int*   modal_ids   = (const int*)  d_in[1];
    const int*   seg_ids     = (const int*)  d_in[2];
    const int*   npi_ids     = (const int*)  d_in[3];
    const int*   posi_ids    = (const int*)  d_in[4];
    const float* age_tau     = (const float*)d_in[5];
    const float* delay_tau   = (const float*)d_in[6];
    const float* word_table  = (const float*)d_in[7];
    const float* modal_table = (const float*)d_in[8];
    const float* seg_table   = (const float*)d_in[9];
    const float* npi_table   = (const float*)d_in[10];
    const float* posi_table  = (const float*)d_in[11];
    const float* age_w       = (const float*)d_in[12];
    const float* age_b       = (const float*)d_in[13];
    const float* age_w0      = (const float*)d_in[14];
    const float* age_b0      = (const float*)d_in[15];
    const float* delay_w     = (const float*)d_in[16];
    const float* delay_b     = (const float*)d_in[17];
    const float* delay_w0    = (const float*)d_in[18];
    const float* delay_b0    = (const float*)d_in[19];
    const float* ln_gamma    = (const float*)d_in[20];
    const float* ln_beta     = (const float*)d_in[21];
    float* out = (float*)d_out;

    dim3 grid(TOKENS / 4);   // 4096 blocks, 4 tokens (waves) each
    dim3 block(256);
    hipLaunchKernelGGL(bert_emb_kernel, grid, block, 0, stream,
                       word_ids, modal_ids, seg_ids, npi_ids, posi_ids,
                       age_tau, delay_tau,
                       word_table, modal_table, seg_table, npi_table, posi_table,
                       age_w, age_b, age_w0, age_b0,
                       delay_w, delay_b, delay_w0, delay_b0,
                       ln_gamma, ln_beta, out);
}